// Round 3
// baseline (640.609 us; speedup 1.0000x reference)
//
#include <hip/hip_runtime.h>
#include <stdint.h>

#define N_  32
#define C_  512
#define T_  2048
#define NB  1024
#define NT  (N_ * T_)          // 65536
#define GB_S 129               // gather buffer stride (+1 pad)

typedef _Float16 h8 __attribute__((ext_vector_type(8)));
typedef _Float16 h4 __attribute__((ext_vector_type(4)));
typedef float    f4 __attribute__((ext_vector_type(4)));

// ws layout (bytes)
// wsf[0]=xnorm2, wsf[1]=scoreSum, wsf[8..1031]=counts, wsf[1032..2055]=cnorm
#define WS_CBH      16384
#define WS_CBL      (WS_CBH + 1048576)
#define WS_XTH      (WS_CBL + 1048576)
#define WS_XTL      (WS_XTH + 67108864)

__device__ __forceinline__ void gll16(const void* g, void* l) {
    __builtin_amdgcn_global_load_lds((const __attribute__((address_space(1))) void*)g,
                                     (__attribute__((address_space(3))) void*)l, 16, 0, 0);
}

// ---------------- init: zero xnorm2, scoreSum, counts ----------------
__global__ void k_init(unsigned* ws32) {
    int g = blockIdx.x * 256 + threadIdx.x;   // grid 5
    if (g < 1032) ws32[g] = 0u;
}

// ---------------- prep: codebook norms + f16 hi/lo split ----------------
// grid 256, one wave per codebook row (4 rows/block)
__global__ __launch_bounds__(256)
void k_prep(const float* __restrict__ cb, float* __restrict__ cnorm,
            _Float16* __restrict__ cbh, _Float16* __restrict__ cbl) {
    const int tid = threadIdx.x;
    const int w = tid >> 6, e = tid & 63;
    const int row = blockIdx.x * 4 + w;
    const float* src = cb + (size_t)row * C_ + e * 8;
    float4 v0 = *(const float4*)src;
    float4 v1 = *(const float4*)(src + 4);
    float fv[8] = {v0.x, v0.y, v0.z, v0.w, v1.x, v1.y, v1.z, v1.w};
    h4 hi0, hi1, lo0, lo1;
    float s = 0.f;
    #pragma unroll
    for (int i = 0; i < 4; ++i) {
        _Float16 h = (_Float16)fv[i];
        hi0[i] = h; lo0[i] = (_Float16)(fv[i] - (float)h);
        s = fmaf(fv[i], fv[i], s);
    }
    #pragma unroll
    for (int i = 0; i < 4; ++i) {
        _Float16 h = (_Float16)fv[4 + i];
        hi1[i] = h; lo1[i] = (_Float16)(fv[4 + i] - (float)h);
        s = fmaf(fv[4 + i], fv[4 + i], s);
    }
    const size_t dst = (size_t)row * C_ + e * 8;
    *(h4*)&cbh[dst] = hi0; *(h4*)&cbh[dst + 4] = hi1;
    *(h4*)&cbl[dst] = lo0; *(h4*)&cbl[dst + 4] = lo1;
    #pragma unroll
    for (int off = 32; off; off >>= 1) s += __shfl_down(s, off, 64);
    if (e == 0) cnorm[row] = s;
}

// ---------------- x (n,c,t) -> xt[(n t)][c] f16 hi/lo + sum(x^2) ----------------
__global__ __launch_bounds__(256)
void k_xt(const float* __restrict__ x,
          _Float16* __restrict__ xth, _Float16* __restrict__ xtl,
          float* __restrict__ xnorm2) {
    __shared__ float Ls[64 * 68];
    __shared__ float red[4];
    const int bx = blockIdx.x;                // grid 8192
    const int n = bx >> 8;
    const int cblk = (bx >> 5) & 7, tblk = bx & 31;
    const int c0 = cblk * 64, t0 = tblk * 64;
    const int tid = threadIdx.x;
    float sq = 0.f;
    #pragma unroll
    for (int ld = 0; ld < 4; ++ld) {
        int idx = tid + ld * 256;
        int cc = idx >> 4, t4 = (idx & 15) << 2;
        float4 v = *(const float4*)&x[((size_t)n * C_ + c0 + cc) * T_ + t0 + t4];
        *(float4*)&Ls[cc * 68 + t4] = v;
        sq = fmaf(v.x, v.x, sq); sq = fmaf(v.y, v.y, sq);
        sq = fmaf(v.z, v.z, sq); sq = fmaf(v.w, v.w, sq);
    }
    __syncthreads();
    const int tt = tid >> 2, cs = (tid & 3) * 16;
    h8 hi0, hi1, lo0, lo1;
    #pragma unroll
    for (int j = 0; j < 8; ++j) {
        float f = Ls[(cs + j) * 68 + tt];
        _Float16 h = (_Float16)f;
        hi0[j] = h; lo0[j] = (_Float16)(f - (float)h);
    }
    #pragma unroll
    for (int j = 0; j < 8; ++j) {
        float f = Ls[(cs + 8 + j) * 68 + tt];
        _Float16 h = (_Float16)f;
        hi1[j] = h; lo1[j] = (_Float16)(f - (float)h);
    }
    const size_t dst = ((size_t)n * T_ + t0 + tt) * C_ + c0 + cs;
    *(h8*)&xth[dst] = hi0; *(h8*)&xth[dst + 8] = hi1;
    *(h8*)&xtl[dst] = lo0; *(h8*)&xtl[dst + 8] = lo1;

    #pragma unroll
    for (int off = 32; off; off >>= 1) sq += __shfl_down(sq, off, 64);
    if ((tid & 63) == 0) red[tid >> 6] = sq;
    __syncthreads();
    if (tid == 0) atomicAdd(xnorm2, red[0] + red[1] + red[2] + red[3]);
}

// ---------------- fused: MFMA GEMM + argmin + gather + out + counts + score ----------------
// grid 512 (128 rows each); A staged in LDS (dbuf), B direct from L2
__global__ __launch_bounds__(256, 2)
void k_gemm(const _Float16* __restrict__ xth, const _Float16* __restrict__ xtl,
            const _Float16* __restrict__ cbh, const _Float16* __restrict__ cbl,
            const float* __restrict__ cnorm, const float* __restrict__ cb,
            float* __restrict__ out, int* __restrict__ counts,
            float* __restrict__ scoreSum) {
    __shared__ float smem_f[8256];           // 33 KB: A dbuf (32KB) / gather buf
    __shared__ unsigned long long rmin[128];
    __shared__ int sidx[128];
    _Float16* smA = (_Float16*)smem_f;

    const int tid = threadIdx.x;
    const int l = tid & 63, w = tid >> 6;
    const int q = l >> 4, r = l & 15;
    const int wm0 = (w & 1) * 64, wn0 = (w >> 1) * 128;
    const int bid = blockIdx.x;
    const int lrow = l >> 2;                  // 0..15
    const int lcol = (l & 3) * 16;            // 0..48 bytes

    if (tid < 128) rmin[tid] = 0xFFFFFFFFFFFFFFFFull;

    const char* gAh = (const char*)xth + ((size_t)bid * 128 + w * 16 + lrow) * 1024 + lcol;
    const char* gAl = (const char*)xtl + ((size_t)bid * 128 + w * 16 + lrow) * 1024 + lcol;
    const int aoff = (wm0 + r) * 32 + q * 8;

    auto stage = [&](int kb) {
        _Float16* d = smA + (kb & 1) * 8192;
        const int kof = kb * 64;
        gll16(gAh + kof,         d + w * 512);
        gll16(gAh + kof + 65536, d + (4 + w) * 512);
        gll16(gAl + kof,         d + 4096 + w * 512);
        gll16(gAl + kof + 65536, d + 4096 + (4 + w) * 512);
    };

    for (int ch = 0; ch < 4; ++ch) {
        const int j0 = ch * 256;
        const char* pBh = (const char*)cbh + (size_t)(j0 + wn0 + r) * 1024 + q * 16;
        const char* pBl = (const char*)cbl + (size_t)(j0 + wn0 + r) * 1024 + q * 16;

        f4 acc[4][8];
        #pragma unroll
        for (int i = 0; i < 4; ++i)
            #pragma unroll
            for (int j = 0; j < 8; ++j)
                acc[i][j] = (f4){0.f, 0.f, 0.f, 0.f};

        stage(0);
        for (int kb = 0; kb < 16; ++kb) {
            __syncthreads();
            if (kb < 15) stage(kb + 1);
            const int kof = kb * 64;
            const _Float16* Ab = smA + (kb & 1) * 8192;

            h8 ah[4], al[4];
            #pragma unroll
            for (int i = 0; i < 4; ++i) {
                ah[i] = *(const h8*)&Ab[aoff + i * 512];
                al[i] = *(const h8*)&Ab[4096 + aoff + i * 512];
            }
            h8 bh[4], bl[4];
            #pragma unroll
            for (int j = 0; j < 4; ++j) {
                bh[j] = *(const h8*)(pBh + kof + j * 16384);
                bl[j] = *(const h8*)(pBl + kof + j * 16384);
            }
            // group 1 MFMA while prefetching group 2 B-frags
            #pragma unroll
            for (int j = 0; j < 4; ++j) {
                h8 bh2 = *(const h8*)(pBh + kof + (j + 4) * 16384);
                h8 bl2 = *(const h8*)(pBl + kof + (j + 4) * 16384);
                #pragma unroll
                for (int i = 0; i < 4; ++i) {
                    acc[i][j] = __builtin_amdgcn_mfma_f32_16x16x32_f16(ah[i], bh[j], acc[i][j], 0, 0, 0);
                    acc[i][j] = __builtin_amdgcn_mfma_f32_16x16x32_f16(al[i], bh[j], acc[i][j], 0, 0, 0);
                    acc[i][j] = __builtin_amdgcn_mfma_f32_16x16x32_f16(ah[i], bl[j], acc[i][j], 0, 0, 0);
                }
                bh[j] = bh2; bl[j] = bl2;
            }
            #pragma unroll
            for (int j = 0; j < 4; ++j)
                #pragma unroll
                for (int i = 0; i < 4; ++i) {
                    acc[i][j + 4] = __builtin_amdgcn_mfma_f32_16x16x32_f16(ah[i], bh[j], acc[i][j + 4], 0, 0, 0);
                    acc[i][j + 4] = __builtin_amdgcn_mfma_f32_16x16x32_f16(al[i], bh[j], acc[i][j + 4], 0, 0, 0);
                    acc[i][j + 4] = __builtin_amdgcn_mfma_f32_16x16x32_f16(ah[i], bl[j], acc[i][j + 4], 0, 0, 0);
                }
        }

        // streaming argmin: score = ||k||^2 - 2*dot; key packs (ordered bits, code)
        float cn[8];
        #pragma unroll
        for (int j = 0; j < 8; ++j) cn[j] = cnorm[j0 + wn0 + j * 16 + r];

        #pragma unroll
        for (int i = 0; i < 4; ++i) {
            #pragma unroll
            for (int rg = 0; rg < 4; ++rg) {
                unsigned long long best = 0xFFFFFFFFFFFFFFFFull;
                #pragma unroll
                for (int j = 0; j < 8; ++j) {
                    float s = fmaf(-2.0f, acc[i][j][rg], cn[j]);
                    unsigned u = __float_as_uint(s);
                    u = (u & 0x80000000u) ? ~u : (u | 0x80000000u);
                    unsigned long long key =
                        ((unsigned long long)u << 32) | (unsigned)(j0 + wn0 + j * 16 + r);
                    best = key < best ? key : best;
                }
                #pragma unroll
                for (int off = 1; off < 16; off <<= 1) {
                    unsigned long long o = __shfl_xor(best, off, 64);
                    best = o < best ? o : best;
                }
                if (r == 0)
                    atomicMin(&rmin[wm0 + i * 16 + q * 4 + rg], best);
            }
        }
        __syncthreads();   // rmin atomics done; also guards smA reuse next chunk
    }

    // decode argmin: codes, counts, score-sum
    if (tid < 128) {
        unsigned long long key = rmin[tid];
        int code = (int)(key & 0xFFFFFFFFull);
        sidx[tid] = code;
        atomicAdd(&counts[code], 1);
        unsigned u = (unsigned)(key >> 32);
        unsigned ob = (u & 0x80000000u) ? (u & 0x7fffffffu) : ~u;
        float s = __uint_as_float(ob);
        #pragma unroll
        for (int off = 32; off; off >>= 1) s += __shfl_down(s, off, 64);
        if ((tid & 63) == 0) atomicAdd(scoreSum, s);
    }
    __syncthreads();

    // gather codebook rows -> LDS transpose -> coalesced out writes
    float* gbuf = smem_f;
    const int n  = bid >> 4;
    const int t0 = (bid & 15) << 7;
    const size_t xbase = (size_t)n * C_ * T_ + t0;
    const int tl   = tid >> 1;
    const int half = tid & 1;
    const int tcol  = tid & 127;
    const int chalf = tid >> 7;

    for (int c0 = 0; c0 < C_; c0 += 64) {
        __syncthreads();
        const int code = sidx[tl];
        const float* src = &cb[(size_t)code * C_ + c0 + half * 32];
        #pragma unroll
        for (int qq = 0; qq < 8; ++qq) {
            float4 v = *(const float4*)&src[qq * 4];
            const int cc = half * 32 + qq * 4;
            gbuf[(cc + 0) * GB_S + tl] = v.x;
            gbuf[(cc + 1) * GB_S + tl] = v.y;
            gbuf[(cc + 2) * GB_S + tl] = v.z;
            gbuf[(cc + 3) * GB_S + tl] = v.w;
        }
        __syncthreads();
        #pragma unroll 8
        for (int i = 0; i < 32; ++i) {
            const int cc = i * 2 + chalf;
            out[xbase + (size_t)(c0 + cc) * T_ + tcol] = gbuf[cc * GB_S + tcol];
        }
    }
}

// ---------------- finalize: perplexity + commit scalars ----------------
__global__ void k_final(const int* __restrict__ counts,
                        const float* __restrict__ wsf,
                        float* __restrict__ out) {
    __shared__ float red[4];
    int tid = threadIdx.x;
    float s = 0.f;
    for (int j = tid; j < NB; j += 256) {
        float p = (float)counts[j] * (1.0f / (float)NT);
        s += p * logf(p + 1e-7f);
    }
    #pragma unroll
    for (int off = 32; off; off >>= 1) s += __shfl_down(s, off, 64);
    if ((tid & 63) == 0) red[tid >> 6] = s;
    __syncthreads();
    if (tid == 0) {
        float H = red[0] + red[1] + red[2] + red[3];
        // commit = (sum x^2 + sum_r min-score_r) / (NT*C)
        out[(size_t)NT * C_]     = (wsf[0] + wsf[1]) * (1.0f / ((float)NT * (float)C_));
        out[(size_t)NT * C_ + 1] = expf(-H);
    }
}

extern "C" void kernel_launch(void* const* d_in, const int* in_sizes, int n_in,
                              void* d_out, int out_size, void* d_ws, size_t ws_size,
                              hipStream_t stream) {
    const float* x  = (const float*)d_in[0];   // (32, 512, 2048)
    const float* cb = (const float*)d_in[1];   // (1024, 512)
    float* out = (float*)d_out;

    char* ws = (char*)d_ws;
    float* wsf = (float*)ws;
    float* xnorm2   = wsf;                     // wsf[0]
    float* scoreSum = wsf + 1;                 // wsf[1]
    int*   counts   = (int*)(wsf + 8);         // wsf[8..1031]
    float* cnorm    = wsf + 1032;              // wsf[1032..2055]
    _Float16* cbh = (_Float16*)(ws + WS_CBH);
    _Float16* cbl = (_Float16*)(ws + WS_CBL);
    _Float16* xth = (_Float16*)(ws + WS_XTH);
    _Float16* xtl = (_Float16*)(ws + WS_XTL);

    k_init<<<5, 256, 0, stream>>>((unsigned*)ws);
    k_prep<<<256, 256, 0, stream>>>(cb, cnorm, cbh, cbl);
    k_xt<<<8192, 256, 0, stream>>>(x, xth, xtl, xnorm2);
    k_gemm<<<512, 256, 0, stream>>>(xth, xtl, cbh, cbl, cnorm, cb, out, counts, scoreSum);
    k_final<<<1, 256, 0, stream>>>(counts, wsf, out);
}